// Round 7
// baseline (237.375 us; speedup 1.0000x reference)
//
#include <hip/hip_runtime.h>
#include <hip/hip_bf16.h>
#include <stdint.h>

typedef unsigned short u16;
typedef __attribute__((ext_vector_type(8))) short short8;
typedef __attribute__((ext_vector_type(4))) float f32x4;

#define B_ 2
#define S_ 2048
#define D_ 1024
#define H_ 16
#define DK_ 64
// scale folded into Q: (1/sqrt(DK)) * log2(e)  -> softmax done with exp2
#define QSCALE 0.18033688011112042f

__device__ __forceinline__ u16 f2bf(float f) {
  union { float f; uint32_t u; } c; c.f = f;
  uint32_t u = c.u;
  u += 0x7fffu + ((u >> 16) & 1u);
  return (u16)(u >> 16);
}

__device__ __forceinline__ uint32_t pk_bf16(float a, float b) {
  __hip_bfloat162 h = __float22bfloat162_rn(float2{a, b});
  union { __hip_bfloat162 h; uint32_t u; } c; c.h = h;
  return c.u;
}

__device__ __forceinline__ float fexp2(float x) {
#if __has_builtin(__builtin_amdgcn_exp2f)
  return __builtin_amdgcn_exp2f(x);
#else
  return exp2f(x);
#endif
}

__device__ __forceinline__ void gll16(const void* g, void* l) {
  __builtin_amdgcn_global_load_lds(
      (const __attribute__((address_space(1))) uint32_t*)g,
      (__attribute__((address_space(3))) uint32_t*)l, 16, 0, 0);
}

// ---------------- fused prep: cast hidden + Wq/Wk/Wv transpose + bias + Wo transpose
__global__ __launch_bounds__(256) void prep_k(const float* __restrict__ hidden,
                                              const float* __restrict__ Wq,
                                              const float* __restrict__ Wk,
                                              const float* __restrict__ Wv,
                                              const float* __restrict__ bq,
                                              const float* __restrict__ bk,
                                              const float* __restrict__ bv,
                                              const float* __restrict__ Wo,
                                              u16* __restrict__ Abf,
                                              u16* __restrict__ Wt,
                                              u16* __restrict__ Wot,
                                              float* __restrict__ biasQKV) {
  __shared__ float t[64][65];
  const int bx = blockIdx.x;
  const int tid = threadIdx.x;

  if (bx < 2048) {
    int i = (bx * 256 + tid) * 8;
    float4 a = *(const float4*)(hidden + i);
    float4 b = *(const float4*)(hidden + i + 4);
    short8 o;
    o[0] = (short)f2bf(a.x); o[1] = (short)f2bf(a.y);
    o[2] = (short)f2bf(a.z); o[3] = (short)f2bf(a.w);
    o[4] = (short)f2bf(b.x); o[5] = (short)f2bf(b.y);
    o[6] = (short)f2bf(b.z); o[7] = (short)f2bf(b.w);
    *(short8*)(Abf + i) = o;
    return;
  }

  if (bx < 2816) {
    const int blk = bx - 2048;
    const int by = blk & 15, z = blk >> 4;
    const int grp = z >> 4, h = z & 15;
    const float* src = (grp == 0) ? Wq : (grp == 1) ? Wk : Wv;
    const float* bsrc = (grp == 0) ? bq : (grp == 1) ? bk : bv;
    const float scale = (grp == 0) ? QSCALE : 1.0f;
    u16* dst = Wt + (size_t)grp * 1024 * 1024;
    const float* Sp = src + (size_t)h * 1024 * 64;
    const int r0 = by * 64;
#pragma unroll
    for (int i = 0; i < 4; i++) {
      int r = i * 16 + (tid >> 4), c = (tid & 15) * 4;
      float4 v = *(const float4*)(Sp + (size_t)(r0 + r) * 64 + c);
      t[r][c] = v.x; t[r][c + 1] = v.y; t[r][c + 2] = v.z; t[r][c + 3] = v.w;
    }
    if (by == 0 && tid < 64)
      biasQKV[grp * 1024 + h * 64 + tid] = bsrc[h * 64 + tid] * scale;
    __syncthreads();
#pragma unroll
    for (int i = 0; i < 4; i++) {
      int c = i * 16 + (tid >> 4), r = (tid & 15) * 4;
      ushort4 o;
      o.x = f2bf(t[r][c] * scale);
      o.y = f2bf(t[r + 1][c] * scale);
      o.z = f2bf(t[r + 2][c] * scale);
      o.w = f2bf(t[r + 3][c] * scale);
      *(ushort4*)(dst + (size_t)(h * 64 + c) * 1024 + r0 + r) = o;
    }
    return;
  }

  {
    const int blk = bx - 2816;
    const int c0 = (blk & 15) * 64, r0 = (blk >> 4) * 64;
#pragma unroll
    for (int i = 0; i < 4; i++) {
      int r = i * 16 + (tid >> 4), c = (tid & 15) * 4;
      float4 v = *(const float4*)(Wo + (size_t)(r0 + r) * 1024 + c0 + c);
      t[r][c] = v.x; t[r][c + 1] = v.y; t[r][c + 2] = v.z; t[r][c + 3] = v.w;
    }
    __syncthreads();
#pragma unroll
    for (int i = 0; i < 4; i++) {
      int c = i * 16 + (tid >> 4), r = (tid & 15) * 4;
      ushort4 o;
      o.x = f2bf(t[r][c]);
      o.y = f2bf(t[r + 1][c]);
      o.z = f2bf(t[r + 2][c]);
      o.w = f2bf(t[r + 3][c]);
      *(ushort4*)(Wot + (size_t)(c0 + c) * 1024 + r0 + r) = o;
    }
  }
}

// ---------------- GEMM 128x128, XOR-swizzled LDS (conflict-free ds_read_b128)
// Store granule g^((r>>1)&3); read col (quad^((l15>>1)&3)). Bank math: 2-way
// (free). C[M][N] = A[M][K]*B^T + bias, out bf16.
__global__ __launch_bounds__(256) void gemm_bt_k(const u16* __restrict__ A,
                                                 const u16* __restrict__ B,
                                                 const float* __restrict__ bias,
                                                 u16* __restrict__ Cout,
                                                 int M, int N, int K) {
  __shared__ u16 As[128 * 32];
  __shared__ u16 Bs[128 * 32];
  const int tid = threadIdx.x;
  const int w = tid >> 6, lane = tid & 63;
  const int wm = w >> 1, wn = w & 1;
  const int m0 = blockIdx.y * 128, n0 = blockIdx.x * 128;
  const int l15 = lane & 15, quad = lane >> 4;
  const int colq = ((quad ^ ((l15 >> 1) & 3)) & 3) * 8;

  int r_st[2], cs_st[2];
#pragma unroll
  for (int i = 0; i < 2; i++) {
    int idx = i * 256 + tid;
    r_st[i] = idx >> 2;
    cs_st[i] = (((idx & 3) ^ ((r_st[i] >> 1) & 3)) & 3) * 8;
  }

  f32x4 acc[4][4];
  const f32x4 zero = {0.f, 0.f, 0.f, 0.f};
#pragma unroll
  for (int i = 0; i < 4; i++)
#pragma unroll
    for (int j = 0; j < 4; j++) acc[i][j] = zero;

  for (int k0 = 0; k0 < K; k0 += 32) {
#pragma unroll
    for (int i = 0; i < 2; i++) {
      gll16(A + (size_t)(m0 + r_st[i]) * K + k0 + cs_st[i], &As[(i * 256 + w * 64) * 8]);
      gll16(B + (size_t)(n0 + r_st[i]) * K + k0 + cs_st[i], &Bs[(i * 256 + w * 64) * 8]);
    }
    __syncthreads();
    short8 af[4], bf[4];
#pragma unroll
    for (int i = 0; i < 4; i++) {
      af[i] = *(const short8*)&As[(wm * 64 + i * 16 + l15) * 32 + colq];
      bf[i] = *(const short8*)&Bs[(wn * 64 + i * 16 + l15) * 32 + colq];
    }
#pragma unroll
    for (int mi = 0; mi < 4; mi++)
#pragma unroll
      for (int ni = 0; ni < 4; ni++)
        acc[mi][ni] = __builtin_amdgcn_mfma_f32_16x16x32_bf16(af[mi], bf[ni], acc[mi][ni], 0, 0, 0);
    __syncthreads();
  }

  const int cm = m0 + wm * 64, cn = n0 + wn * 64;
#pragma unroll
  for (int ni = 0; ni < 4; ni++) {
    int n = cn + ni * 16 + l15;
    float bv = bias[n];
#pragma unroll
    for (int mi = 0; mi < 4; mi++) {
#pragma unroll
      for (int r = 0; r < 4; r++) {
        int m = cm + mi * 16 + quad * 4 + r;
        Cout[(size_t)m * N + n] = f2bf(acc[mi][ni][r] + bv);
      }
    }
  }
}

// ---------------- GEMM 64x128 tile, fp32 out (out projection), swizzled ------
__global__ __launch_bounds__(256) void gemm_bt64_k(const u16* __restrict__ A,
                                                   const u16* __restrict__ B,
                                                   const float* __restrict__ bias,
                                                   float* __restrict__ Cout,
                                                   int M, int N, int K) {
  __shared__ u16 As[64 * 32];
  __shared__ u16 Bs[128 * 32];
  const int tid = threadIdx.x;
  const int w = tid >> 6, lane = tid & 63;
  const int wm = w >> 1, wn = w & 1;
  const int m0 = blockIdx.y * 64, n0 = blockIdx.x * 128;
  const int l15 = lane & 15, quad = lane >> 4;
  const int colq = ((quad ^ ((l15 >> 1) & 3)) & 3) * 8;

  int r_st[2], cs_st[2];
#pragma unroll
  for (int i = 0; i < 2; i++) {
    int idx = i * 256 + tid;
    r_st[i] = idx >> 2;
    cs_st[i] = (((idx & 3) ^ ((r_st[i] >> 1) & 3)) & 3) * 8;
  }

  f32x4 acc[2][4];
  const f32x4 zero = {0.f, 0.f, 0.f, 0.f};
#pragma unroll
  for (int i = 0; i < 2; i++)
#pragma unroll
    for (int j = 0; j < 4; j++) acc[i][j] = zero;

  for (int k0 = 0; k0 < K; k0 += 32) {
    gll16(A + (size_t)(m0 + r_st[0]) * K + k0 + cs_st[0], &As[(w * 64) * 8]);
#pragma unroll
    for (int i = 0; i < 2; i++)
      gll16(B + (size_t)(n0 + r_st[i]) * K + k0 + cs_st[i], &Bs[(i * 256 + w * 64) * 8]);
    __syncthreads();
    short8 af[2], bf[4];
#pragma unroll
    for (int i = 0; i < 2; i++)
      af[i] = *(const short8*)&As[(wm * 32 + i * 16 + l15) * 32 + colq];
#pragma unroll
    for (int j = 0; j < 4; j++)
      bf[j] = *(const short8*)&Bs[(wn * 64 + j * 16 + l15) * 32 + colq];
#pragma unroll
    for (int i = 0; i < 2; i++)
#pragma unroll
      for (int j = 0; j < 4; j++)
        acc[i][j] = __builtin_amdgcn_mfma_f32_16x16x32_bf16(af[i], bf[j], acc[i][j], 0, 0, 0);
    __syncthreads();
  }

  const int cm = m0 + wm * 32, cn = n0 + wn * 64;
#pragma unroll
  for (int j = 0; j < 4; j++) {
    int n = cn + j * 16 + l15;
    float bv = bias[n];
#pragma unroll
    for (int i = 0; i < 2; i++) {
#pragma unroll
      for (int r = 0; r < 4; r++) {
        int m = cm + i * 16 + quad * 4 + r;
        Cout[(size_t)m * N + n] = acc[i][j][r] + bv;
      }
    }
  }
}

// ---------------- V transpose: qkv V region -> Vt [b][h][v][s] bf16 ----------------
__global__ __launch_bounds__(256) void transpose_v_k(const u16* __restrict__ qkv,
                                                     u16* __restrict__ Vt) {
  __shared__ u16 t[64][71];
  const int b = blockIdx.z, h = blockIdx.y, s0 = blockIdx.x * 64;
  const int tid = threadIdx.x;
#pragma unroll
  for (int i = 0; i < 2; i++) {
    int s = i * 32 + (tid >> 3), v = (tid & 7) * 8;
    short8 val = *(const short8*)(qkv + (size_t)(b * S_ + s0 + s) * 3072 + 2048 + h * 64 + v);
#pragma unroll
    for (int j = 0; j < 8; j++) t[s][v + j] = (u16)val[j];
  }
  __syncthreads();
#pragma unroll
  for (int i = 0; i < 2; i++) {
    int v = i * 32 + (tid >> 3), s8 = (tid & 7) * 8;
    short8 o;
#pragma unroll
    for (int j = 0; j < 8; j++) o[j] = (short)t[s8 + j][v];
    *(short8*)(Vt + ((size_t)(b * H_ + h) * 64 + v) * S_ + s0 + s8) = o;
  }
}

// ---------------- flash attention v5: dbuf + 64 q-rows + 3 blocks/CU ----------
// grid (S/64, H, B) = 1024 blocks; 4 waves x 16 q-rows. LDS 41 KB -> 3
// blocks/CU = 12 waves/CU. Double-buffered staging, ONE barrier per iter.
// XOR-swizzled K/V tiles; no-max exp2 softmax; S^T orientation; P transposes
// through wave-private stride-72 LDS.
__global__ __launch_bounds__(256) void attn_k(const u16* __restrict__ qkv,
                                              const u16* __restrict__ Vt,
                                              u16* __restrict__ ctx) {
  __shared__ u16 Ks[2][64 * 64];
  __shared__ u16 Vs[2][64 * 64];
  __shared__ u16 Pb[4][16 * 72];
  const int tid = threadIdx.x;
  const int w = tid >> 6, lane = tid & 63;
  const int l15 = lane & 15, quad = lane >> 4;
  const int b = blockIdx.z, h = blockIdx.y, q0 = blockIdx.x * 64;

  // Q fragments (B-operand for S^T): row q0 + w*16 + l15
  const u16* qbase = qkv + (size_t)(b * S_ + q0 + w * 16 + l15) * 3072 + h * 64;
  short8 qf0 = *(const short8*)(qbase + quad * 8);
  short8 qf1 = *(const short8*)(qbase + 32 + quad * 8);

  // swizzled read columns (granule ^ (l15&7)), halves 0/1 of dk/key
  const int col0 = ((quad ^ (l15 & 7)) & 7) * 8;
  const int col1 = (((4 + quad) ^ (l15 & 7)) & 7) * 8;

  // staging: idx = i*256+tid ; r=idx>>3, g=idx&7; src col = (g^(r&7))*8
  int r_st[2], cs_st[2];
#pragma unroll
  for (int i = 0; i < 2; i++) {
    int idx = i * 256 + tid;
    r_st[i] = idx >> 3;
    cs_st[i] = ((idx & 7) ^ (r_st[i] & 7)) * 8;
  }
  const u16* kp[2];
  const u16* vp[2];
#pragma unroll
  for (int i = 0; i < 2; i++) {
    kp[i] = qkv + (size_t)(b * S_ + r_st[i]) * 3072 + 1024 + h * 64 + cs_st[i];
    vp[i] = Vt + ((size_t)(b * H_ + h) * 64 + r_st[i]) * S_ + cs_st[i];
  }

  const f32x4 zero = {0.f, 0.f, 0.f, 0.f};
  f32x4 o[4];
#pragma unroll
  for (int i = 0; i < 4; i++) o[i] = zero;
  float lsum = 0.f;
  u16* pw = &Pb[w][0];

  auto stage = [&](int bb, int t) {
#pragma unroll
    for (int i = 0; i < 2; i++) {
      gll16(kp[i] + (size_t)t * 64 * 3072, &Ks[bb][(i * 256 + w * 64) * 8]);
      gll16(vp[i] + t * 64, &Vs[bb][(i * 256 + w * 64) * 8]);
    }
  };

  auto compute = [&](int bb) {
    // S^T = K Q^T : C[m=key=quad*4+r][n=qrow=l15]
#pragma unroll
    for (int kt = 0; kt < 4; kt++) {
      const int krow = (kt * 16 + l15) * 64;
      short8 k0 = *(const short8*)&Ks[bb][krow + col0];
      short8 k1 = *(const short8*)&Ks[bb][krow + col1];
      f32x4 st = __builtin_amdgcn_mfma_f32_16x16x32_bf16(k0, qf0, zero, 0, 0, 0);
      st = __builtin_amdgcn_mfma_f32_16x16x32_bf16(k1, qf1, st, 0, 0, 0);
      float p0 = fexp2(st[0]), p1 = fexp2(st[1]), p2 = fexp2(st[2]), p3 = fexp2(st[3]);
      lsum += (p0 + p1) + (p2 + p3);
      uint2 pk;
      pk.x = pk_bf16(p0, p1);
      pk.y = pk_bf16(p2, p3);
      *(uint2*)&pw[l15 * 72 + kt * 16 + quad * 4] = pk;
    }
    short8 pf0 = *(const short8*)&pw[l15 * 72 + quad * 8];
    short8 pf1 = *(const short8*)&pw[l15 * 72 + 32 + quad * 8];
    // O^T += Vt . P^T : C[m=v][n=qrow]
#pragma unroll
    for (int vi = 0; vi < 4; vi++) {
      const int vrow = (vi * 16 + l15) * 64;
      short8 v0 = *(const short8*)&Vs[bb][vrow + col0];
      short8 v1 = *(const short8*)&Vs[bb][vrow + col1];
      o[vi] = __builtin_amdgcn_mfma_f32_16x16x32_bf16(v0, pf0, o[vi], 0, 0, 0);
      o[vi] = __builtin_amdgcn_mfma_f32_16x16x32_bf16(v1, pf1, o[vi], 0, 0, 0);
    }
  };

  stage(0, 0);
  for (int t = 0; t < 31; t++) {
    __syncthreads();
    stage((t + 1) & 1, t + 1);
    compute(t & 1);
  }
  __syncthreads();
  compute(1);  // t=31 -> buffer 1

  lsum += __shfl_xor(lsum, 16);
  lsum += __shfl_xor(lsum, 32);
  const float inv = 1.f / lsum;

  u16* cbase = ctx + (size_t)(b * S_ + q0 + w * 16 + l15) * 1024 + h * 64;
#pragma unroll
  for (int vi = 0; vi < 4; vi++) {
    ushort4 pk;
    pk.x = f2bf(o[vi][0] * inv);
    pk.y = f2bf(o[vi][1] * inv);
    pk.z = f2bf(o[vi][2] * inv);
    pk.w = f2bf(o[vi][3] * inv);
    *(ushort4*)(cbase + vi * 16 + quad * 4) = pk;
  }
}

extern "C" void kernel_launch(void* const* d_in, const int* in_sizes, int n_in,
                              void* d_out, int out_size, void* d_ws, size_t ws_size,
                              hipStream_t stream) {
  const float* hidden = (const float*)d_in[0];
  const float* Wq = (const float*)d_in[1];
  const float* bq = (const float*)d_in[2];
  const float* Wk = (const float*)d_in[3];
  const float* bk = (const float*)d_in[4];
  const float* Wv = (const float*)d_in[5];
  const float* bv = (const float*)d_in[6];
  const float* Wo = (const float*)d_in[7];
  const float* bo = (const float*)d_in[8];
  float* out = (float*)d_out;

  char* ws = (char*)d_ws;
  u16* Abf = (u16*)(ws + 0);                 // 4096x1024 bf16   (8,388,608)
  u16* Wt = (u16*)(ws + 8388608);            // 3072x1024 bf16   (6,291,456)
  u16* Wot = (u16*)(ws + 14680064);          // 1024x1024 bf16   (2,097,152)
  float* biasQKV = (float*)(ws + 16777216);  // 3072 fp32        (12,288 padded)
  u16* qkv = (u16*)(ws + 16789504);          // 4096x3072 bf16   (25,165,824)
  u16* Vt = (u16*)(ws + 41955328);           // [b][h][64][2048] (8,388,608)
  u16* ctx = (u16*)(ws + 50343936);          // 4096x1024 bf16   (8,388,608)

  // fused prep: cast + Wq/Wk/Wv transpose + bias + Wo transpose
  prep_k<<<3072, 256, 0, stream>>>(hidden, Wq, Wk, Wv, bq, bk, bv, Wo,
                                   Abf, Wt, Wot, biasQKV);

  // QKV projection: [4096,1024] x [3072,1024]^T -> [4096,3072] bf16
  gemm_bt_k<<<dim3(24, 32), 256, 0, stream>>>(Abf, Wt, biasQKV, qkv, 4096, 3072, 1024);

  // V transpose for PV A-operand
  transpose_v_k<<<dim3(32, 16, 2), 256, 0, stream>>>(qkv, Vt);

  // flash attention -> ctx [4096, 1024] bf16
  attn_k<<<dim3(32, 16, 2), 256, 0, stream>>>(qkv, Vt, ctx);

  // output projection: [4096,1024] x [1024,1024]^T + bo -> fp32 out
  gemm_bt64_k<<<dim3(8, 64), 256, 0, stream>>>(ctx, Wot, bo, out, 4096, 1024, 1024);
}

// Round 8
// 212.272 us; speedup vs baseline: 1.1183x; 1.1183x over previous
//
#include <hip/hip_runtime.h>
#include <hip/hip_bf16.h>
#include <stdint.h>

typedef unsigned short u16;
typedef __attribute__((ext_vector_type(8))) short short8;
typedef __attribute__((ext_vector_type(4))) float f32x4;

#define B_ 2
#define S_ 2048
#define D_ 1024
#define H_ 16
#define DK_ 64
// scale folded into Q: (1/sqrt(DK)) * log2(e)  -> softmax done with exp2
#define QSCALE 0.18033688011112042f

__device__ __forceinline__ u16 f2bf(float f) {
  union { float f; uint32_t u; } c; c.f = f;
  uint32_t u = c.u;
  u += 0x7fffu + ((u >> 16) & 1u);
  return (u16)(u >> 16);
}

__device__ __forceinline__ uint32_t pk_bf16(float a, float b) {
  __hip_bfloat162 h = __float22bfloat162_rn(float2{a, b});
  union { __hip_bfloat162 h; uint32_t u; } c; c.h = h;
  return c.u;
}

__device__ __forceinline__ float fexp2(float x) {
#if __has_builtin(__builtin_amdgcn_exp2f)
  return __builtin_amdgcn_exp2f(x);
#else
  return exp2f(x);
#endif
}

__device__ __forceinline__ void gll16(const void* g, void* l) {
  __builtin_amdgcn_global_load_lds(
      (const __attribute__((address_space(1))) uint32_t*)g,
      (__attribute__((address_space(3))) uint32_t*)l, 16, 0, 0);
}

// ---------------- fused prep: cast hidden + Wq/Wk/Wv transpose + bias + Wo transpose
__global__ __launch_bounds__(256) void prep_k(const float* __restrict__ hidden,
                                              const float* __restrict__ Wq,
                                              const float* __restrict__ Wk,
                                              const float* __restrict__ Wv,
                                              const float* __restrict__ bq,
                                              const float* __restrict__ bk,
                                              const float* __restrict__ bv,
                                              const float* __restrict__ Wo,
                                              u16* __restrict__ Abf,
                                              u16* __restrict__ Wt,
                                              u16* __restrict__ Wot,
                                              float* __restrict__ biasQKV) {
  __shared__ float t[64][65];
  const int bx = blockIdx.x;
  const int tid = threadIdx.x;

  if (bx < 2048) {
    int i = (bx * 256 + tid) * 8;
    float4 a = *(const float4*)(hidden + i);
    float4 b = *(const float4*)(hidden + i + 4);
    short8 o;
    o[0] = (short)f2bf(a.x); o[1] = (short)f2bf(a.y);
    o[2] = (short)f2bf(a.z); o[3] = (short)f2bf(a.w);
    o[4] = (short)f2bf(b.x); o[5] = (short)f2bf(b.y);
    o[6] = (short)f2bf(b.z); o[7] = (short)f2bf(b.w);
    *(short8*)(Abf + i) = o;
    return;
  }

  if (bx < 2816) {
    const int blk = bx - 2048;
    const int by = blk & 15, z = blk >> 4;
    const int grp = z >> 4, h = z & 15;
    const float* src = (grp == 0) ? Wq : (grp == 1) ? Wk : Wv;
    const float* bsrc = (grp == 0) ? bq : (grp == 1) ? bk : bv;
    const float scale = (grp == 0) ? QSCALE : 1.0f;
    u16* dst = Wt + (size_t)grp * 1024 * 1024;
    const float* Sp = src + (size_t)h * 1024 * 64;
    const int r0 = by * 64;
#pragma unroll
    for (int i = 0; i < 4; i++) {
      int r = i * 16 + (tid >> 4), c = (tid & 15) * 4;
      float4 v = *(const float4*)(Sp + (size_t)(r0 + r) * 64 + c);
      t[r][c] = v.x; t[r][c + 1] = v.y; t[r][c + 2] = v.z; t[r][c + 3] = v.w;
    }
    if (by == 0 && tid < 64)
      biasQKV[grp * 1024 + h * 64 + tid] = bsrc[h * 64 + tid] * scale;
    __syncthreads();
#pragma unroll
    for (int i = 0; i < 4; i++) {
      int c = i * 16 + (tid >> 4), r = (tid & 15) * 4;
      ushort4 o;
      o.x = f2bf(t[r][c] * scale);
      o.y = f2bf(t[r + 1][c] * scale);
      o.z = f2bf(t[r + 2][c] * scale);
      o.w = f2bf(t[r + 3][c] * scale);
      *(ushort4*)(dst + (size_t)(h * 64 + c) * 1024 + r0 + r) = o;
    }
    return;
  }

  {
    const int blk = bx - 2816;
    const int c0 = (blk & 15) * 64, r0 = (blk >> 4) * 64;
#pragma unroll
    for (int i = 0; i < 4; i++) {
      int r = i * 16 + (tid >> 4), c = (tid & 15) * 4;
      float4 v = *(const float4*)(Wo + (size_t)(r0 + r) * 1024 + c0 + c);
      t[r][c] = v.x; t[r][c + 1] = v.y; t[r][c + 2] = v.z; t[r][c + 3] = v.w;
    }
    __syncthreads();
#pragma unroll
    for (int i = 0; i < 4; i++) {
      int c = i * 16 + (tid >> 4), r = (tid & 15) * 4;
      ushort4 o;
      o.x = f2bf(t[r][c]);
      o.y = f2bf(t[r + 1][c]);
      o.z = f2bf(t[r + 2][c]);
      o.w = f2bf(t[r + 3][c]);
      *(ushort4*)(Wot + (size_t)(c0 + c) * 1024 + r0 + r) = o;
    }
  }
}

// ---------------- QKV GEMM 128x128, swizzled LDS; V-columns write Vt directly
// C[M][N] = A[M][K]*B^T + bias. Columns n<2048 (Q,K) -> qkv[m][n] bf16.
// Columns n>=2048 (V) -> Vt[(b*H+h)*64+v][s] (transposed store from the
// accumulator fragment; 16 rows x 32B segments). qkv V region never written.
__global__ __launch_bounds__(256) void gemm_qkv_k(const u16* __restrict__ A,
                                                  const u16* __restrict__ B,
                                                  const float* __restrict__ bias,
                                                  u16* __restrict__ qkv,
                                                  u16* __restrict__ Vt) {
  const int M_ = 4096, N_ = 3072, K_ = 1024;
  __shared__ u16 As[128 * 32];
  __shared__ u16 Bs[128 * 32];
  const int tid = threadIdx.x;
  const int w = tid >> 6, lane = tid & 63;
  const int wm = w >> 1, wn = w & 1;
  const int m0 = blockIdx.y * 128, n0 = blockIdx.x * 128;
  const int l15 = lane & 15, quad = lane >> 4;
  const int colq = ((quad ^ ((l15 >> 1) & 3)) & 3) * 8;

  int r_st[2], cs_st[2];
#pragma unroll
  for (int i = 0; i < 2; i++) {
    int idx = i * 256 + tid;
    r_st[i] = idx >> 2;
    cs_st[i] = (((idx & 3) ^ ((r_st[i] >> 1) & 3)) & 3) * 8;
  }

  f32x4 acc[4][4];
  const f32x4 zero = {0.f, 0.f, 0.f, 0.f};
#pragma unroll
  for (int i = 0; i < 4; i++)
#pragma unroll
    for (int j = 0; j < 4; j++) acc[i][j] = zero;

  for (int k0 = 0; k0 < K_; k0 += 32) {
#pragma unroll
    for (int i = 0; i < 2; i++) {
      gll16(A + (size_t)(m0 + r_st[i]) * K_ + k0 + cs_st[i], &As[(i * 256 + w * 64) * 8]);
      gll16(B + (size_t)(n0 + r_st[i]) * K_ + k0 + cs_st[i], &Bs[(i * 256 + w * 64) * 8]);
    }
    __syncthreads();
    short8 af[4], bf[4];
#pragma unroll
    for (int i = 0; i < 4; i++) {
      af[i] = *(const short8*)&As[(wm * 64 + i * 16 + l15) * 32 + colq];
      bf[i] = *(const short8*)&Bs[(wn * 64 + i * 16 + l15) * 32 + colq];
    }
#pragma unroll
    for (int mi = 0; mi < 4; mi++)
#pragma unroll
      for (int ni = 0; ni < 4; ni++)
        acc[mi][ni] = __builtin_amdgcn_mfma_f32_16x16x32_bf16(af[mi], bf[ni], acc[mi][ni], 0, 0, 0);
    __syncthreads();
  }

  const int cm = m0 + wm * 64, cn = n0 + wn * 64;
  if (cn < 2048) {
    // Q/K columns -> qkv[m][n]
#pragma unroll
    for (int ni = 0; ni < 4; ni++) {
      int n = cn + ni * 16 + l15;
      float bv = bias[n];
#pragma unroll
      for (int mi = 0; mi < 4; mi++) {
#pragma unroll
        for (int r = 0; r < 4; r++) {
          int m = cm + mi * 16 + quad * 4 + r;
          qkv[(size_t)m * 3072 + n] = f2bf(acc[mi][ni][r] + bv);
        }
      }
    }
  } else {
    // V columns -> Vt[(b*H+h)*64+v][s]  (transposed store)
    const int b = cm >> 11;       // batch of this row-block (cm % 2048 stays in-batch)
    const int s0 = cm & 2047;
#pragma unroll
    for (int ni = 0; ni < 4; ni++) {
      int n = cn + ni * 16 + l15;
      float bv = bias[n];
      const int hv = n - 2048;                   // h*64 + v
      u16* vrow = Vt + ((size_t)(b * H_) * 64 + hv) * S_ + s0;
#pragma unroll
      for (int mi = 0; mi < 4; mi++) {
        ushort4 pk;
        pk.x = f2bf(acc[mi][ni][0] + bv);
        pk.y = f2bf(acc[mi][ni][1] + bv);
        pk.z = f2bf(acc[mi][ni][2] + bv);
        pk.w = f2bf(acc[mi][ni][3] + bv);
        *(ushort4*)(vrow + mi * 16 + quad * 4) = pk;
      }
    }
  }
}

// ---------------- GEMM 64x128 tile, fp32 out (out projection), swizzled ------
__global__ __launch_bounds__(256) void gemm_bt64_k(const u16* __restrict__ A,
                                                   const u16* __restrict__ B,
                                                   const float* __restrict__ bias,
                                                   float* __restrict__ Cout,
                                                   int M, int N, int K) {
  __shared__ u16 As[64 * 32];
  __shared__ u16 Bs[128 * 32];
  const int tid = threadIdx.x;
  const int w = tid >> 6, lane = tid & 63;
  const int wm = w >> 1, wn = w & 1;
  const int m0 = blockIdx.y * 64, n0 = blockIdx.x * 128;
  const int l15 = lane & 15, quad = lane >> 4;
  const int colq = ((quad ^ ((l15 >> 1) & 3)) & 3) * 8;

  int r_st[2], cs_st[2];
#pragma unroll
  for (int i = 0; i < 2; i++) {
    int idx = i * 256 + tid;
    r_st[i] = idx >> 2;
    cs_st[i] = (((idx & 3) ^ ((r_st[i] >> 1) & 3)) & 3) * 8;
  }

  f32x4 acc[2][4];
  const f32x4 zero = {0.f, 0.f, 0.f, 0.f};
#pragma unroll
  for (int i = 0; i < 2; i++)
#pragma unroll
    for (int j = 0; j < 4; j++) acc[i][j] = zero;

  for (int k0 = 0; k0 < K; k0 += 32) {
    gll16(A + (size_t)(m0 + r_st[0]) * K + k0 + cs_st[0], &As[(w * 64) * 8]);
#pragma unroll
    for (int i = 0; i < 2; i++)
      gll16(B + (size_t)(n0 + r_st[i]) * K + k0 + cs_st[i], &Bs[(i * 256 + w * 64) * 8]);
    __syncthreads();
    short8 af[2], bf[4];
#pragma unroll
    for (int i = 0; i < 2; i++)
      af[i] = *(const short8*)&As[(wm * 32 + i * 16 + l15) * 32 + colq];
#pragma unroll
    for (int j = 0; j < 4; j++)
      bf[j] = *(const short8*)&Bs[(wn * 64 + j * 16 + l15) * 32 + colq];
#pragma unroll
    for (int i = 0; i < 2; i++)
#pragma unroll
      for (int j = 0; j < 4; j++)
        acc[i][j] = __builtin_amdgcn_mfma_f32_16x16x32_bf16(af[i], bf[j], acc[i][j], 0, 0, 0);
    __syncthreads();
  }

  const int cm = m0 + wm * 32, cn = n0 + wn * 64;
#pragma unroll
  for (int j = 0; j < 4; j++) {
    int n = cn + j * 16 + l15;
    float bv = bias[n];
#pragma unroll
    for (int i = 0; i < 2; i++) {
#pragma unroll
      for (int r = 0; r < 4; r++) {
        int m = cm + i * 16 + quad * 4 + r;
        Cout[(size_t)m * N + n] = acc[i][j][r] + bv;
      }
    }
  }
}

// ---------------- flash attention (R4 config: 128 q-rows, dbuf, 1 barrier) ---
// grid (S/128, H, B) = 512; 4 waves x 32 q-rows (2 row-tiles of 16).
// Double-buffered K/V staging: stage tile t+1 right after the barrier, compute
// tile t. XOR-swizzled tiles; no-max exp2 softmax; S^T orientation; P through
// wave-private stride-72 LDS. Best measured attn variant: ~60 us.
__global__ __launch_bounds__(256) void attn_k(const u16* __restrict__ qkv,
                                              const u16* __restrict__ Vt,
                                              u16* __restrict__ ctx) {
  __shared__ u16 Ks[2][64 * 64];
  __shared__ u16 Vs[2][64 * 64];
  __shared__ u16 Pb[4][32 * 72];
  const int tid = threadIdx.x;
  const int w = tid >> 6, lane = tid & 63;
  const int l15 = lane & 15, quad = lane >> 4;
  const int b = blockIdx.z, h = blockIdx.y, q0 = blockIdx.x * 128;

  // Q fragments (B-operand for S^T): rows q0 + w*32 + rt*16 + l15
  short8 qf[2][2];
#pragma unroll
  for (int rt = 0; rt < 2; rt++) {
    const u16* qbase = qkv + (size_t)(b * S_ + q0 + w * 32 + rt * 16 + l15) * 3072 + h * 64;
    qf[rt][0] = *(const short8*)(qbase + quad * 8);
    qf[rt][1] = *(const short8*)(qbase + 32 + quad * 8);
  }

  // swizzled read columns (granule ^ (l15&7)), halves 0/1
  const int col0 = ((quad ^ (l15 & 7)) & 7) * 8;
  const int col1 = (((4 + quad) ^ (l15 & 7)) & 7) * 8;

  // staging source offsets: idx = i*256+tid ; r=idx>>3, g=idx&7; src col = g^(r&7)
  int r_st[2], cs_st[2];
#pragma unroll
  for (int i = 0; i < 2; i++) {
    int idx = i * 256 + tid;
    r_st[i] = idx >> 3;
    cs_st[i] = ((idx & 7) ^ (r_st[i] & 7)) * 8;
  }
  const u16* kp[2];
  const u16* vp[2];
#pragma unroll
  for (int i = 0; i < 2; i++) {
    kp[i] = qkv + (size_t)(b * S_ + r_st[i]) * 3072 + 1024 + h * 64 + cs_st[i];
    vp[i] = Vt + ((size_t)(b * H_ + h) * 64 + r_st[i]) * S_ + cs_st[i];
  }

  const f32x4 zero = {0.f, 0.f, 0.f, 0.f};
  f32x4 o[2][4];
#pragma unroll
  for (int rt = 0; rt < 2; rt++)
#pragma unroll
    for (int i = 0; i < 4; i++) o[rt][i] = zero;
  float lsum[2] = {0.f, 0.f};
  u16* pw = &Pb[w][0];

  auto stage = [&](int bb, int t) {
#pragma unroll
    for (int i = 0; i < 2; i++) {
      gll16(kp[i] + (size_t)t * 64 * 3072, &Ks[bb][(i * 256 + w * 64) * 8]);
      gll16(vp[i] + t * 64, &Vs[bb][(i * 256 + w * 64) * 8]);
    }
  };

  auto compute = [&](int bb) {
    short8 kf[4][2];
#pragma unroll
    for (int t = 0; t < 4; t++) {
      const int krow = (t * 16 + l15) * 64;
      kf[t][0] = *(const short8*)&Ks[bb][krow + col0];
      kf[t][1] = *(const short8*)&Ks[bb][krow + col1];
    }
#pragma unroll
    for (int rt = 0; rt < 2; rt++) {
#pragma unroll
      for (int t = 0; t < 4; t++) {
        f32x4 st = __builtin_amdgcn_mfma_f32_16x16x32_bf16(kf[t][0], qf[rt][0], zero, 0, 0, 0);
        st = __builtin_amdgcn_mfma_f32_16x16x32_bf16(kf[t][1], qf[rt][1], st, 0, 0, 0);
        float p0 = fexp2(st[0]), p1 = fexp2(st[1]), p2 = fexp2(st[2]), p3 = fexp2(st[3]);
        lsum[rt] += (p0 + p1) + (p2 + p3);
        uint2 pk;
        pk.x = pk_bf16(p0, p1);
        pk.y = pk_bf16(p2, p3);
        *(uint2*)&pw[(rt * 16 + l15) * 72 + t * 16 + quad * 4] = pk;
      }
    }
    short8 pf[2][2];
#pragma unroll
    for (int rt = 0; rt < 2; rt++) {
      pf[rt][0] = *(const short8*)&pw[(rt * 16 + l15) * 72 + quad * 8];
      pf[rt][1] = *(const short8*)&pw[(rt * 16 + l15) * 72 + 32 + quad * 8];
    }
#pragma unroll
    for (int vi = 0; vi < 4; vi++) {
      const int vrow = (vi * 16 + l15) * 64;
      short8 v0 = *(const short8*)&Vs[bb][vrow + col0];
      short8 v1 = *(const short8*)&Vs[bb][vrow + col1];
#pragma unroll
      for (int rt = 0; rt < 2; rt++) {
        o[rt][vi] = __builtin_amdgcn_mfma_f32_16x16x32_bf16(v0, pf[rt][0], o[rt][vi], 0, 0, 0);
        o[rt][vi] = __builtin_amdgcn_mfma_f32_16x16x32_bf16(v1, pf[rt][1], o[rt][vi], 0, 0, 0);
      }
    }
  };

  stage(0, 0);
  for (int t = 0; t < 31; t++) {
    __syncthreads();
    stage((t + 1) & 1, t + 1);
    compute(t & 1);
  }
  __syncthreads();
  compute(1);  // t=31 -> buffer 1

#pragma unroll
  for (int rt = 0; rt < 2; rt++) {
    float ls = lsum[rt];
    ls += __shfl_xor(ls, 16);
    ls += __shfl_xor(ls, 32);
    const float inv = 1.f / ls;
    u16* cbase = ctx + (size_t)(b * S_ + q0 + w * 32 + rt * 16 + l15) * 1024 + h * 64;
#pragma unroll
    for (int vi = 0; vi < 4; vi++) {
      ushort4 pk;
      pk.x = f2bf(o[rt][vi][0] * inv);
      pk.y = f2bf(o[rt][vi][1] * inv);
      pk.z = f2bf(o[rt][vi][2] * inv);
      pk.w = f2bf(o[rt][vi][3] * inv);
      *(ushort4*)(cbase + vi * 16 + quad * 4) = pk;
    }
  }
}

extern "C" void kernel_launch(void* const* d_in, const int* in_sizes, int n_in,
                              void* d_out, int out_size, void* d_ws, size_t ws_size,
                              hipStream_t stream) {
  const float* hidden = (const float*)d_in[0];
  const float* Wq = (const float*)d_in[1];
  const float* bq = (const float*)d_in[2];
  const float* Wk = (const float*)d_in[3];
  const float* bk = (const float*)d_in[4];
  const float* Wv = (const float*)d_in[5];
  const float* bv = (const float*)d_in[6];
  const float* Wo = (const float*)d_in[7];
  const float* bo = (const float*)d_in[8];
  float* out = (float*)d_out;

  char* ws = (char*)d_ws;
  u16* Abf = (u16*)(ws + 0);                 // 4096x1024 bf16   (8,388,608)
  u16* Wt = (u16*)(ws + 8388608);            // 3072x1024 bf16   (6,291,456)
  u16* Wot = (u16*)(ws + 14680064);          // 1024x1024 bf16   (2,097,152)
  float* biasQKV = (float*)(ws + 16777216);  // 3072 fp32        (12,288 padded)
  u16* qkv = (u16*)(ws + 16789504);          // 4096x3072 bf16 (Q,K regions used)
  u16* Vt = (u16*)(ws + 41955328);           // [b][h][64][2048] (8,388,608)
  u16* ctx = (u16*)(ws + 50343936);          // 4096x1024 bf16   (8,388,608)

  // fused prep: cast + Wq/Wk/Wv transpose + bias + Wo transpose
  prep_k<<<3072, 256, 0, stream>>>(hidden, Wq, Wk, Wv, bq, bk, bv, Wo,
                                   Abf, Wt, Wot, biasQKV);

  // QKV projection; V columns transposed directly into Vt
  gemm_qkv_k<<<dim3(24, 32), 256, 0, stream>>>(Abf, Wt, biasQKV, qkv, Vt);

  // flash attention -> ctx [4096, 1024] bf16
  attn_k<<<dim3(16, 16, 2), 256, 0, stream>>>(qkv, Vt, ctx);

  // output projection: [4096,1024] x [1024,1024]^T + bo -> fp32 out
  gemm_bt64_k<<<dim3(8, 64), 256, 0, stream>>>(ctx, Wot, bo, out, 4096, 1024, 1024);
}

// Round 9
// 209.623 us; speedup vs baseline: 1.1324x; 1.0126x over previous
//
#include <hip/hip_runtime.h>
#include <hip/hip_bf16.h>
#include <stdint.h>

typedef unsigned short u16;
typedef __attribute__((ext_vector_type(8))) short short8;
typedef __attribute__((ext_vector_type(4))) float f32x4;

#define B_ 2
#define S_ 2048
#define D_ 1024
#define H_ 16
#define DK_ 64
// scale folded into Q: (1/sqrt(DK)) * log2(e)  -> softmax done with exp2
#define QSCALE 0.18033688011112042f

__device__ __forceinline__ u16 f2bf(float f) {
  union { float f; uint32_t u; } c; c.f = f;
  uint32_t u = c.u;
  u += 0x7fffu + ((u >> 16) & 1u);
  return (u16)(u >> 16);
}

__device__ __forceinline__ uint32_t pk_bf16(float a, float b) {
  __hip_bfloat162 h = __float22bfloat162_rn(float2{a, b});
  union { __hip_bfloat162 h; uint32_t u; } c; c.h = h;
  return c.u;
}

__device__ __forceinline__ float fexp2(float x) {
#if __has_builtin(__builtin_amdgcn_exp2f)
  return __builtin_amdgcn_exp2f(x);
#else
  return exp2f(x);
#endif
}

__device__ __forceinline__ void gll16(const void* g, void* l) {
  __builtin_amdgcn_global_load_lds(
      (const __attribute__((address_space(1))) uint32_t*)g,
      (__attribute__((address_space(3))) uint32_t*)l, 16, 0, 0);
}

// ---------------- fused prep: cast hidden + Wq/Wk/Wv transpose + bias + Wo transpose
__global__ __launch_bounds__(256) void prep_k(const float* __restrict__ hidden,
                                              const float* __restrict__ Wq,
                                              const float* __restrict__ Wk,
                                              const float* __restrict__ Wv,
                                              const float* __restrict__ bq,
                                              const float* __restrict__ bk,
                                              const float* __restrict__ bv,
                                              const float* __restrict__ Wo,
                                              u16* __restrict__ Abf,
                                              u16* __restrict__ Wt,
                                              u16* __restrict__ Wot,
                                              float* __restrict__ biasQKV) {
  __shared__ float t[64][65];
  const int bx = blockIdx.x;
  const int tid = threadIdx.x;

  if (bx < 2048) {
    int i = (bx * 256 + tid) * 8;
    float4 a = *(const float4*)(hidden + i);
    float4 b = *(const float4*)(hidden + i + 4);
    short8 o;
    o[0] = (short)f2bf(a.x); o[1] = (short)f2bf(a.y);
    o[2] = (short)f2bf(a.z); o[3] = (short)f2bf(a.w);
    o[4] = (short)f2bf(b.x); o[5] = (short)f2bf(b.y);
    o[6] = (short)f2bf(b.z); o[7] = (short)f2bf(b.w);
    *(short8*)(Abf + i) = o;
    return;
  }

  if (bx < 2816) {
    const int blk = bx - 2048;
    const int by = blk & 15, z = blk >> 4;
    const int grp = z >> 4, h = z & 15;
    const float* src = (grp == 0) ? Wq : (grp == 1) ? Wk : Wv;
    const float* bsrc = (grp == 0) ? bq : (grp == 1) ? bk : bv;
    const float scale = (grp == 0) ? QSCALE : 1.0f;
    u16* dst = Wt + (size_t)grp * 1024 * 1024;
    const float* Sp = src + (size_t)h * 1024 * 64;
    const int r0 = by * 64;
#pragma unroll
    for (int i = 0; i < 4; i++) {
      int r = i * 16 + (tid >> 4), c = (tid & 15) * 4;
      float4 v = *(const float4*)(Sp + (size_t)(r0 + r) * 64 + c);
      t[r][c] = v.x; t[r][c + 1] = v.y; t[r][c + 2] = v.z; t[r][c + 3] = v.w;
    }
    if (by == 0 && tid < 64)
      biasQKV[grp * 1024 + h * 64 + tid] = bsrc[h * 64 + tid] * scale;
    __syncthreads();
#pragma unroll
    for (int i = 0; i < 4; i++) {
      int c = i * 16 + (tid >> 4), r = (tid & 15) * 4;
      ushort4 o;
      o.x = f2bf(t[r][c] * scale);
      o.y = f2bf(t[r + 1][c] * scale);
      o.z = f2bf(t[r + 2][c] * scale);
      o.w = f2bf(t[r + 3][c] * scale);
      *(ushort4*)(dst + (size_t)(h * 64 + c) * 1024 + r0 + r) = o;
    }
    return;
  }

  {
    const int blk = bx - 2816;
    const int c0 = (blk & 15) * 64, r0 = (blk >> 4) * 64;
#pragma unroll
    for (int i = 0; i < 4; i++) {
      int r = i * 16 + (tid >> 4), c = (tid & 15) * 4;
      float4 v = *(const float4*)(Wo + (size_t)(r0 + r) * 1024 + c0 + c);
      t[r][c] = v.x; t[r][c + 1] = v.y; t[r][c + 2] = v.z; t[r][c + 3] = v.w;
    }
    __syncthreads();
#pragma unroll
    for (int i = 0; i < 4; i++) {
      int c = i * 16 + (tid >> 4), r = (tid & 15) * 4;
      ushort4 o;
      o.x = f2bf(t[r][c]);
      o.y = f2bf(t[r + 1][c]);
      o.z = f2bf(t[r + 2][c]);
      o.w = f2bf(t[r + 3][c]);
      *(ushort4*)(Wot + (size_t)(c0 + c) * 1024 + r0 + r) = o;
    }
  }
}

// ---------------- QKV GEMM 128x128, BK=64, XOR-swizzled LDS ------------------
// 32 MFMA per wave per barrier-pair (2x BK=32) -> half the barrier drains.
// LDS 32 KB. Store granule g^(r&7); read granule (kk*4+quad)^(l15&7) -> 2-way
// bank aliasing (free). C[M=4096][N=3072] = A*B^T + bias, out bf16.
__global__ __launch_bounds__(256) void gemm_bt_k(const u16* __restrict__ A,
                                                 const u16* __restrict__ B,
                                                 const float* __restrict__ bias,
                                                 u16* __restrict__ Cout,
                                                 int M, int N, int K) {
  __shared__ u16 As[128 * 64];
  __shared__ u16 Bs[128 * 64];
  const int tid = threadIdx.x;
  const int w = tid >> 6, lane = tid & 63;
  const int wm = w >> 1, wn = w & 1;
  const int m0 = blockIdx.y * 128, n0 = blockIdx.x * 128;
  const int l15 = lane & 15, quad = lane >> 4;
  // read columns for kk=0,1: wanted granule kk*4+quad, stored at ^(row&7)
  const int colr[2] = {(((quad) ^ (l15 & 7)) & 7) * 8,
                       (((4 + quad) ^ (l15 & 7)) & 7) * 8};

  // staging: 1024 chunks per matrix; idx = i*256+tid; r=idx>>3, g=idx&7;
  // source col = (g ^ (r&7))*8  (dest is linear lane order, wave-uniform base)
  int r_st[4], cs_st[4];
#pragma unroll
  for (int i = 0; i < 4; i++) {
    int idx = i * 256 + tid;
    r_st[i] = idx >> 3;
    cs_st[i] = ((idx & 7) ^ (r_st[i] & 7)) * 8;
  }

  f32x4 acc[4][4];
  const f32x4 zero = {0.f, 0.f, 0.f, 0.f};
#pragma unroll
  for (int i = 0; i < 4; i++)
#pragma unroll
    for (int j = 0; j < 4; j++) acc[i][j] = zero;

  for (int k0 = 0; k0 < K; k0 += 64) {
#pragma unroll
    for (int i = 0; i < 4; i++) {
      gll16(A + (size_t)(m0 + r_st[i]) * K + k0 + cs_st[i], &As[(i * 256 + w * 64) * 8]);
      gll16(B + (size_t)(n0 + r_st[i]) * K + k0 + cs_st[i], &Bs[(i * 256 + w * 64) * 8]);
    }
    __syncthreads();
#pragma unroll
    for (int kk = 0; kk < 2; kk++) {
      short8 af[4], bf[4];
#pragma unroll
      for (int i = 0; i < 4; i++) {
        af[i] = *(const short8*)&As[(wm * 64 + i * 16 + l15) * 64 + colr[kk]];
        bf[i] = *(const short8*)&Bs[(wn * 64 + i * 16 + l15) * 64 + colr[kk]];
      }
#pragma unroll
      for (int mi = 0; mi < 4; mi++)
#pragma unroll
        for (int ni = 0; ni < 4; ni++)
          acc[mi][ni] = __builtin_amdgcn_mfma_f32_16x16x32_bf16(af[mi], bf[ni], acc[mi][ni], 0, 0, 0);
    }
    __syncthreads();
  }

  const int cm = m0 + wm * 64, cn = n0 + wn * 64;
#pragma unroll
  for (int ni = 0; ni < 4; ni++) {
    int n = cn + ni * 16 + l15;
    float bv = bias[n];
#pragma unroll
    for (int mi = 0; mi < 4; mi++) {
#pragma unroll
      for (int r = 0; r < 4; r++) {
        int m = cm + mi * 16 + quad * 4 + r;
        Cout[(size_t)m * N + n] = f2bf(acc[mi][ni][r] + bv);
      }
    }
  }
}

// ---------------- GEMM 64x128 tile, fp32 out (out projection), swizzled ------
__global__ __launch_bounds__(256) void gemm_bt64_k(const u16* __restrict__ A,
                                                   const u16* __restrict__ B,
                                                   const float* __restrict__ bias,
                                                   float* __restrict__ Cout,
                                                   int M, int N, int K) {
  __shared__ u16 As[64 * 32];
  __shared__ u16 Bs[128 * 32];
  const int tid = threadIdx.x;
  const int w = tid >> 6, lane = tid & 63;
  const int wm = w >> 1, wn = w & 1;
  const int m0 = blockIdx.y * 64, n0 = blockIdx.x * 128;
  const int l15 = lane & 15, quad = lane >> 4;
  const int colq = ((quad ^ ((l15 >> 1) & 3)) & 3) * 8;

  int r_st[2], cs_st[2];
#pragma unroll
  for (int i = 0; i < 2; i++) {
    int idx = i * 256 + tid;
    r_st[i] = idx >> 2;
    cs_st[i] = (((idx & 3) ^ ((r_st[i] >> 1) & 3)) & 3) * 8;
  }

  f32x4 acc[2][4];
  const f32x4 zero = {0.f, 0.f, 0.f, 0.f};
#pragma unroll
  for (int i = 0; i < 2; i++)
#pragma unroll
    for (int j = 0; j < 4; j++) acc[i][j] = zero;

  for (int k0 = 0; k0 < K; k0 += 32) {
    gll16(A + (size_t)(m0 + r_st[0]) * K + k0 + cs_st[0], &As[(w * 64) * 8]);
#pragma unroll
    for (int i = 0; i < 2; i++)
      gll16(B + (size_t)(n0 + r_st[i]) * K + k0 + cs_st[i], &Bs[(i * 256 + w * 64) * 8]);
    __syncthreads();
    short8 af[2], bf[4];
#pragma unroll
    for (int i = 0; i < 2; i++)
      af[i] = *(const short8*)&As[(wm * 32 + i * 16 + l15) * 32 + colq];
#pragma unroll
    for (int j = 0; j < 4; j++)
      bf[j] = *(const short8*)&Bs[(wn * 64 + j * 16 + l15) * 32 + colq];
#pragma unroll
    for (int i = 0; i < 2; i++)
#pragma unroll
      for (int j = 0; j < 4; j++)
        acc[i][j] = __builtin_amdgcn_mfma_f32_16x16x32_bf16(af[i], bf[j], acc[i][j], 0, 0, 0);
    __syncthreads();
  }

  const int cm = m0 + wm * 32, cn = n0 + wn * 64;
#pragma unroll
  for (int j = 0; j < 4; j++) {
    int n = cn + j * 16 + l15;
    float bv = bias[j ? n : n];
    bv = bias[n];
#pragma unroll
    for (int i = 0; i < 2; i++) {
#pragma unroll
      for (int r = 0; r < 4; r++) {
        int m = cm + i * 16 + quad * 4 + r;
        Cout[(size_t)m * N + n] = acc[i][j][r] + bv;
      }
    }
  }
}

// ---------------- V transpose: qkv V region -> Vt [b][h][v][s] bf16 ----------------
__global__ __launch_bounds__(256) void transpose_v_k(const u16* __restrict__ qkv,
                                                     u16* __restrict__ Vt) {
  __shared__ u16 t[64][71];
  const int b = blockIdx.z, h = blockIdx.y, s0 = blockIdx.x * 64;
  const int tid = threadIdx.x;
#pragma unroll
  for (int i = 0; i < 2; i++) {
    int s = i * 32 + (tid >> 3), v = (tid & 7) * 8;
    short8 val = *(const short8*)(qkv + (size_t)(b * S_ + s0 + s) * 3072 + 2048 + h * 64 + v);
#pragma unroll
    for (int j = 0; j < 8; j++) t[s][v + j] = (u16)val[j];
  }
  __syncthreads();
#pragma unroll
  for (int i = 0; i < 2; i++) {
    int v = i * 32 + (tid >> 3), s8 = (tid & 7) * 8;
    short8 o;
#pragma unroll
    for (int j = 0; j < 8; j++) o[j] = (short)t[s8 + j][v];
    *(short8*)(Vt + ((size_t)(b * H_ + h) * 64 + v) * S_ + s0 + s8) = o;
  }
}

// ---------------- flash attention (R4 config: 128 q-rows, dbuf, 1 barrier) ---
// Best measured attn variant (~60-62 us). Near its LDS-pipe roofline (~86%
// busy at 2 blocks/CU) — do not tweak without cutting LDS traffic.
__global__ __launch_bounds__(256) void attn_k(const u16* __restrict__ qkv,
                                              const u16* __restrict__ Vt,
                                              u16* __restrict__ ctx) {
  __shared__ u16 Ks[2][64 * 64];
  __shared__ u16 Vs[2][64 * 64];
  __shared__ u16 Pb[4][32 * 72];
  const int tid = threadIdx.x;
  const int w = tid >> 6, lane = tid & 63;
  const int l15 = lane & 15, quad = lane >> 4;
  const int b = blockIdx.z, h = blockIdx.y, q0 = blockIdx.x * 128;

  short8 qf[2][2];
#pragma unroll
  for (int rt = 0; rt < 2; rt++) {
    const u16* qbase = qkv + (size_t)(b * S_ + q0 + w * 32 + rt * 16 + l15) * 3072 + h * 64;
    qf[rt][0] = *(const short8*)(qbase + quad * 8);
    qf[rt][1] = *(const short8*)(qbase + 32 + quad * 8);
  }

  const int col0 = ((quad ^ (l15 & 7)) & 7) * 8;
  const int col1 = (((4 + quad) ^ (l15 & 7)) & 7) * 8;

  int r_st[2], cs_st[2];
#pragma unroll
  for (int i = 0; i < 2; i++) {
    int idx = i * 256 + tid;
    r_st[i] = idx >> 3;
    cs_st[i] = ((idx & 7) ^ (r_st[i] & 7)) * 8;
  }
  const u16* kp[2];
  const u16* vp[2];
#pragma unroll
  for (int i = 0; i < 2; i++) {
    kp[i] = qkv + (size_t)(b * S_ + r_st[i]) * 3072 + 1024 + h * 64 + cs_st[i];
    vp[i] = Vt + ((size_t)(b * H_ + h) * 64 + r_st[i]) * S_ + cs_st[i];
  }

  const f32x4 zero = {0.f, 0.f, 0.f, 0.f};
  f32x4 o[2][4];
#pragma unroll
  for (int rt = 0; rt < 2; rt++)
#pragma unroll
    for (int i = 0; i < 4; i++) o[rt][i] = zero;
  float lsum[2] = {0.f, 0.f};
  u16* pw = &Pb[w][0];

  auto stage = [&](int bb, int t) {
#pragma unroll
    for (int i = 0; i < 2; i++) {
      gll16(kp[i] + (size_t)t * 64 * 3072, &Ks[bb][(i * 256 + w * 64) * 8]);
      gll16(vp[i] + t * 64, &Vs[bb][(i * 256 + w * 64) * 8]);
    }
  };

  auto compute = [&](int bb) {
    short8 kf[4][2];
#pragma unroll
    for (int t = 0; t < 4; t++) {
      const int krow = (t * 16 + l15) * 64;
      kf[t][0] = *(const short8*)&Ks[bb][krow + col0];
      kf[t][1] = *(const short8*)&Ks[bb][krow + col1];
    }
#pragma unroll
    for (int rt = 0; rt < 2; rt++) {
#pragma unroll
      for (int t = 0; t < 4; t++) {
        f32x4 st = __builtin_amdgcn_mfma_f32_16x16x32_bf16(kf[t][0], qf[rt][0], zero, 0, 0, 0);
        st = __builtin_amdgcn_mfma_f32_16x16x32_bf16(kf[t][1], qf[rt][1], st, 0, 0, 0);
        float p0 = fexp2(st[0]), p1 = fexp2(st[1]), p2 = fexp2(st[2]), p3 = fexp2(st[3]);
        lsum[rt] += (p0 + p1) + (p2 + p3);
        uint2 pk;
        pk.x = pk_bf16(p0, p1);
        pk.y = pk_bf16(p2, p3);
        *(uint2*)&pw[(rt * 16 + l15) * 72 + t * 16 + quad * 4] = pk;
      }
    }
    short8 pf[2][2];
#pragma unroll
    for (int rt = 0; rt < 2; rt++) {
      pf[rt][0] = *(const short8*)&pw[(rt * 16 + l15) * 72 + quad * 8];
      pf[rt][1] = *(const short8*)&pw[(rt * 16 + l15) * 72 + 32 + quad * 8];
    }
#pragma unroll
    for (int vi = 0; vi < 4; vi++) {
      const int vrow = (vi * 16 + l15) * 64;
      short8 v0 = *(const short8*)&Vs[bb][vrow + col0];
      short8 v1 = *(const short8*)&Vs[bb][vrow + col1];
#pragma unroll
      for (int rt = 0; rt < 2; rt++) {
        o[rt][vi] = __builtin_amdgcn_mfma_f32_16x16x32_bf16(v0, pf[rt][0], o[rt][vi], 0, 0, 0);
        o[rt][vi] = __builtin_amdgcn_mfma_f32_16x16x32_bf16(v1, pf[rt][1], o[rt][vi], 0, 0, 0);
      }
    }
  };

  stage(0, 0);
  for (int t = 0; t < 31; t++) {
    __syncthreads();
    stage((t + 1) & 1, t + 1);
    compute(t & 1);
  }
  __syncthreads();
  compute(1);

#pragma unroll
  for (int rt = 0; rt < 2; rt++) {
    float ls = lsum[rt];
    ls += __shfl_xor(ls, 16);
    ls += __shfl_xor(ls, 32);
    const float inv = 1.f / ls;
    u16* cbase = ctx + (size_t)(b * S_ + q0 + w * 32 + rt * 16 + l15) * 1024 + h * 64;
#pragma unroll
    for (int vi = 0; vi < 4; vi++) {
      ushort4 pk;
      pk.x = f2bf(o[rt][vi][0] * inv);
      pk.y = f2bf(o[rt][vi][1] * inv);
      pk.z = f2bf(o[rt][vi][2] * inv);
      pk.w = f2bf(o[rt][vi][3] * inv);
      *(ushort4*)(cbase + vi * 16 + quad * 4) = pk;
    }
  }
}

extern "C" void kernel_launch(void* const* d_in, const int* in_sizes, int n_in,
                              void* d_out, int out_size, void* d_ws, size_t ws_size,
                              hipStream_t stream) {
  const float* hidden = (const float*)d_in[0];
  const float* Wq = (const float*)d_in[1];
  const float* bq = (const float*)d_in[2];
  const float* Wk = (const float*)d_in[3];
  const float* bk = (const float*)d_in[4];
  const float* Wv = (const float*)d_in[5];
  const float* bv = (const float*)d_in[6];
  const float* Wo = (const float*)d_in[7];
  const float* bo = (const float*)d_in[8];
  float* out = (float*)d_out;

  char* ws = (char*)d_ws;
  u16* Abf = (u16*)(ws + 0);                 // 4096x1024 bf16   (8,388,608)
  u16* Wt = (u16*)(ws + 8388608);            // 3072x1024 bf16   (6,291,456)
  u16* Wot = (u16*)(ws + 14680064);          // 1024x1024 bf16   (2,097,152)
  float* biasQKV = (float*)(ws + 16777216);  // 3072 fp32        (12,288 padded)
  u16* qkv = (u16*)(ws + 16789504);          // 4096x3072 bf16   (25,165,824)
  u16* Vt = (u16*)(ws + 41955328);           // [b][h][64][2048] (8,388,608)
  u16* ctx = (u16*)(ws + 50343936);          // 4096x1024 bf16   (8,388,608)

  // fused prep: cast + Wq/Wk/Wv transpose + bias + Wo transpose
  prep_k<<<3072, 256, 0, stream>>>(hidden, Wq, Wk, Wv, bq, bk, bv, Wo,
                                   Abf, Wt, Wot, biasQKV);

  // QKV projection: [4096,1024] x [3072,1024]^T -> [4096,3072] bf16 (BK=64)
  gemm_bt_k<<<dim3(24, 32), 256, 0, stream>>>(Abf, Wt, biasQKV, qkv, 4096, 3072, 1024);

  // V transpose for PV A-operand
  transpose_v_k<<<dim3(32, 16, 2), 256, 0, stream>>>(qkv, Vt);

  // flash attention -> ctx [4096, 1024] bf16
  attn_k<<<dim3(16, 16, 2), 256, 0, stream>>>(qkv, Vt, ctx);

  // output projection: [4096,1024] x [1024,1024]^T + bo -> fp32 out
  gemm_bt64_k<<<dim3(8, 64), 256, 0, stream>>>(ctx, Wot, bo, out, 4096, 1024, 1024);
}